// Round 9
// baseline (426.092 us; speedup 1.0000x reference)
//
#include <hip/hip_runtime.h>
#include <stdint.h>

#define Bn 32
#define Nn 1723
#define Cn 512
#define Hn 256
#define MTA 54    // ceil(1723/32): stage-A tiles == supT sub-steps
#define KSB 54    // stage-B K-steps of 32

typedef __bf16 bf16x8 __attribute__((ext_vector_type(8)));
typedef float f32x4 __attribute__((ext_vector_type(4)));
typedef unsigned short u16;

__device__ __forceinline__ u16 f2b(float f){
  union{float f; uint32_t i;} c; c.f=f; uint32_t u=c.i;
  u += 0x7fffu + ((u>>16)&1u);
  return (u16)(u>>16);
}
__device__ __forceinline__ bf16x8 ld8(const u16* p){
  union{ uint4 u; bf16x8 b; } c;
  c.u = *reinterpret_cast<const uint4*>(p);
  return c.b;
}
__device__ __forceinline__ f32x4 mfma16(bf16x8 a, bf16x8 b, f32x4 c){
  return __builtin_amdgcn_mfma_f32_16x16x32_bf16(a,b,c,0,0,0);
}
__device__ __forceinline__ bf16x8 cvt8(float4 a, float4 b){
  union{ uint32_t w[4]; bf16x8 v; } r;
  asm("v_cvt_pk_bf16_f32 %0, %1, %2" : "=v"(r.w[0]) : "v"(a.x), "v"(a.y));
  asm("v_cvt_pk_bf16_f32 %0, %1, %2" : "=v"(r.w[1]) : "v"(a.z), "v"(a.w));
  asm("v_cvt_pk_bf16_f32 %0, %1, %2" : "=v"(r.w[2]) : "v"(b.x), "v"(b.y));
  asm("v_cvt_pk_bf16_f32 %0, %1, %2" : "=v"(r.w[3]) : "v"(b.z), "v"(b.w));
  return r.v;
}
// counted-vmcnt barrier: keep N youngest VMEM ops in flight across the barrier
#define BARV(n) do{ asm volatile("s_waitcnt vmcnt(" #n ") lgkmcnt(0)" ::: "memory"); \
                    __builtin_amdgcn_s_barrier(); \
                    asm volatile("" ::: "memory"); }while(0)
#define CFENCE() asm volatile("" ::: "memory")
#define GLD_LDS16(gp, lp) \
  __builtin_amdgcn_global_load_lds((const __attribute__((address_space(1))) void*)(gp), \
                                   (__attribute__((address_space(3))) void*)(lp), 16, 0, 0)

// ---- kernel 0: weights -> bf16 MFMA-fragment-major (validated R5) ----
__global__ __launch_bounds__(256) void k_prep(
    const float* __restrict__ W1, const float* __restrict__ Wc, const float* __restrict__ W2,
    u16* __restrict__ W1f, u16* __restrict__ WcTf, u16* __restrict__ W2f)
{
  const int t = blockIdx.x*256 + threadIdx.x;
  const int lane = t & 63, unit = t >> 6;
  const int lr = lane & 15, lh = lane >> 4;
  const float* src; u16* dst; int K, tile, kk; bool tr = false;
  if (unit < 256){ tile = unit>>4; kk = unit&15; src = W1; dst = W1f; K = 512; }
  else if (unit < 384){ int u = unit-256; tile = u>>3; kk = u&7; src = Wc; dst = WcTf; K = 256; tr = true; }
  else { int u = unit-384; tile = u>>3; kk = u&7; src = W2; dst = W2f; K = 256; }
  const int row = tile*16 + lr;
  const int k0 = kk*32 + lh*8;
  union{u16 s[8]; uint4 u;} o;
  #pragma unroll
  for (int j=0;j<8;++j){
    float v = tr ? src[(size_t)(k0+j)*256 + row] : src[(size_t)row*K + k0 + j];
    o.s[j] = f2b(v);
  }
  *reinterpret_cast<uint4*>(dst + (size_t)(tile*(K/32)+kk)*512 + lane*8) = o.u;
}

// ---------------- stage A (R5-validated; phantom vertices now ZEROED in supT) ----------------
__global__ __launch_bounds__(256) void k_stageA(
    const float* __restrict__ x, const float* __restrict__ prw, const float* __restrict__ prb,
    const u16* __restrict__ W1f, const float* __restrict__ b1,
    const float* __restrict__ n1w, const float* __restrict__ n1b,
    const u16* __restrict__ WcTf, u16* __restrict__ supT)
{
  __shared__ u16 t1[32*512];
  __shared__ float ps[2][32], pq[2][32];
  u16* const t2 = t1;
  const int b = blockIdx.y;
  const int m0 = blockIdx.x*32;
  const int tid = threadIdx.x;
  const int w = tid>>6, l = tid&63, lr = l&15, lh = l>>4;
  const int wm = w>>1, wn = w&1;

  float pw[8], pb[8];
  #pragma unroll
  for (int j=0;j<8;++j){ pw[j]=prw[l*8+j]; pb[j]=prb[l*8+j]; }
  #pragma unroll
  for (int rr=0; rr<8; ++rr){
    const int rloc = w*8+rr;
    int rg = m0 + rloc; rg = rg < Nn ? rg : Nn-1;
    const float* src = x + ((size_t)b*Nn + rg)*Cn + l*8;
    float4 c0 = *reinterpret_cast<const float4*>(src);
    float4 c1 = *reinterpret_cast<const float4*>(src+4);
    float v[8] = {c0.x,c0.y,c0.z,c0.w,c1.x,c1.y,c1.z,c1.w};
    float s=0.f, q=0.f;
    #pragma unroll
    for (int j=0;j<8;++j){ s+=v[j]; q+=v[j]*v[j]; }
    #pragma unroll
    for (int m=1;m<64;m<<=1){ s += __shfl_xor(s,m); q += __shfl_xor(q,m); }
    const float mean = s*(1.f/Cn);
    const float rstd = rsqrtf(fmaxf(q*(1.f/Cn) - mean*mean, 0.f) + 1e-12f);
    union{uint4 u; u16 s[8];} ov;
    #pragma unroll
    for (int j=0;j<8;++j){
      float t = (v[j]-mean)*rstd*pw[j] + pb[j];
      ov.s[j] = f2b(fmaxf(t,0.f));
    }
    const int idx = (rloc*512 + l*8) ^ ((rloc&7)<<3);
    *reinterpret_cast<uint4*>(&t1[idx]) = ov.u;
  }
  __syncthreads();

  f32x4 acc[8];
  #pragma unroll
  for (int i=0;i<8;++i) acc[i] = f32x4{0.f,0.f,0.f,0.f};
  const int arow = wm*16 + lr;
  const int aswz = (arow&7)<<3;
  for (int kk=0; kk<16; ++kk){
    bf16x8 a = ld8(&t1[(arow*512 + kk*32 + lh*8) ^ aswz]);
    #pragma unroll
    for (int nt=0; nt<8; ++nt){
      bf16x8 bb = ld8(W1f + (size_t)(((wn*8+nt)*16 + kk))*512 + l*8);
      acc[nt] = mfma16(a, bb, acc[nt]);
    }
  }

  float sum[4]={0,0,0,0}, sq[4]={0,0,0,0};
  #pragma unroll
  for (int nt=0; nt<8; ++nt){
    const float bias = b1[wn*128+nt*16+lr];
    #pragma unroll
    for (int r=0;r<4;++r){
      float vv = acc[nt][r] + bias;
      acc[nt][r] = vv; sum[r]+=vv; sq[r]+=vv*vv;
    }
  }
  #pragma unroll
  for (int m=1;m<16;m<<=1){
    #pragma unroll
    for (int r=0;r<4;++r){ sum[r]+=__shfl_xor(sum[r],m); sq[r]+=__shfl_xor(sq[r],m); }
  }
  if (lr==0){
    #pragma unroll
    for (int r=0;r<4;++r){
      const int row = wm*16 + lh*4 + r;
      ps[wn][row]=sum[r]; pq[wn][row]=sq[r];
    }
  }
  __syncthreads();
  float mean[4], rstd[4];
  #pragma unroll
  for (int r=0;r<4;++r){
    const int row = wm*16 + lh*4 + r;
    const float S = ps[0][row]+ps[1][row];
    const float Q = pq[0][row]+pq[1][row];
    const float mu = S*(1.f/Hn);
    mean[r] = mu;
    rstd[r] = rsqrtf(fmaxf(Q*(1.f/Hn) - mu*mu, 0.f) + 1e-12f);
  }
  #pragma unroll
  for (int nt=0; nt<8; ++nt){
    const int col = wn*128+nt*16+lr;
    const float nw = n1w[col], nb = n1b[col];
    #pragma unroll
    for (int r=0;r<4;++r){
      const int row = wm*16 + lh*4 + r;
      float t = (acc[nt][r]-mean[r])*rstd[r]*nw + nb;
      t2[(row*256 + col) ^ ((row&7)<<3)] = f2b(fmaxf(t,0.f));
    }
  }
  __syncthreads();

  f32x4 acc2[8];
  #pragma unroll
  for (int i=0;i<8;++i) acc2[i] = f32x4{0.f,0.f,0.f,0.f};
  for (int kk=0; kk<8; ++kk){
    bf16x8 a = ld8(&t2[(arow*256 + kk*32 + lh*8) ^ aswz]);
    #pragma unroll
    for (int nt=0; nt<8; ++nt){
      bf16x8 bb = ld8(WcTf + (size_t)(((wn*8+nt)*8 + kk))*512 + l*8);
      acc2[nt] = mfma16(a, bb, acc2[nt]);
    }
  }

  // fragment-major supT write; ZERO phantom vertices (v >= Nn) so stage B needs no k-mask
  const int off512 = (wm*2 + (lh>>1))*128 + lr*8 + (lh&1)*4;
  const int vbase = m0 + wm*16 + lh*4;
  #pragma unroll
  for (int nt=0; nt<8; ++nt){
    const int htile = wn*8 + nt;
    const size_t base = ((size_t)(b*16 + htile)*MTA + blockIdx.x)*512 + off512;
    ushort4 o;
    o.x = (vbase+0 < Nn) ? f2b(acc2[nt][0]) : (u16)0;
    o.y = (vbase+1 < Nn) ? f2b(acc2[nt][1]) : (u16)0;
    o.z = (vbase+2 < Nn) ? f2b(acc2[nt][2]) : (u16)0;
    o.w = (vbase+3 < Nn) ? f2b(acc2[nt][3]) : (u16)0;
    *reinterpret_cast<ushort4*>(supT + base) = o;
  }
}

// ---------------- stage B: global_load_lds 3-buffer pipeline ----------------
// grid 1728 = 8 XCD x (4 b x 54 tiles of 32 rows). 4 waves/block.
// adj staged f32 via global_load_lds (1KB/wave/step), source pre-swizzled
// (32B-block XOR row&3); counted vmcnt(1) barriers; bv reg double-set.
__global__ __launch_bounds__(256) void k_stageB(
    const float* __restrict__ adj, const u16* __restrict__ supT,
    const float* __restrict__ cb, const float* __restrict__ n2w, const float* __restrict__ n2b,
    const u16* __restrict__ W2f, const float* __restrict__ bl2,
    const float* __restrict__ x, float* __restrict__ out)
{
  __shared__ float atile[3][32*32];  // 12 KB: 3 bufs of 32 rows x 32 f32
  __shared__ u16 t3[32*256];         // 16 KB
  __shared__ float ps[4][32], pq[4][32];
  const int bid = blockIdx.x;
  const int xcd = bid & 7, idx = bid >> 3;
  const int b = xcd*4 + (idx & 3);          // 4 consecutive b per XCD (supT L2-resident)
  const int m0 = (idx >> 2) * 32;
  const int tid = threadIdx.x, w = tid>>6, l = tid&63, lr = l&15, lh = l>>4;

  const float* adjb = adj + (size_t)b*Nn*Nn;
  const u16* supb = supT + (size_t)b*16*MTA*512;
  const float* gmax = adj + ((size_t)Bn*Nn*Nn - 4);   // clamp: last safe float4

  // per-lane gll source geometry (row/chunk fixed; column varies with step)
  int grow = m0 + 8*w + (l>>3); grow = grow < Nn ? grow : Nn-1;
  const int pch = l&7;
  const int gcolbase = (((pch>>1) ^ (grow&3))<<3) + ((pch&1)<<2);
  const float* gbase = adjb + (size_t)grow*Nn + gcolbase;
  float* const lbase = &atile[0][0] + w*256;          // wave-uniform dest (rows 8w..8w+7)

  #define GLL(c, s) do{                                                  \
    const float* gp = gbase + (s)*32;                                    \
    if (gp > gmax) gp = gmax;                                            \
    GLD_LDS16(gp, lbase + (c)*1024);                                     \
  }while(0)

  #define BVLOAD(bvr, sub) do{                                           \
    _Pragma("unroll")                                                    \
    for (int nt=0;nt<4;++nt)                                             \
      bvr[nt] = ld8(supb + (size_t)((w*4+nt)*MTA + (sub))*512 + l*8);    \
  }while(0)

  #define MSTEP(c, bvr) do{                                              \
    _Pragma("unroll")                                                    \
    for (int mt=0;mt<2;++mt){                                            \
      const int ar = mt*16+lr;                                           \
      const float* ap = &atile[0][0] + (c)*1024 + ar*32 + ((lh ^ (ar&3))<<3); \
      float4 v0 = *reinterpret_cast<const float4*>(ap);                  \
      float4 v1 = *reinterpret_cast<const float4*>(ap+4);                \
      bf16x8 af = cvt8(v0, v1);                                          \
      _Pragma("unroll")                                                  \
      for (int nt=0;nt<4;++nt) acc1[mt][nt] = mfma16(af, bvr[nt], acc1[mt][nt]); \
    }                                                                    \
  }while(0)

  bf16x8 bvA[4], bvB[4];
  f32x4 acc1[2][4];
  #pragma unroll
  for (int i=0;i<2;++i)
    #pragma unroll
    for (int j=0;j<4;++j) acc1[i][j] = f32x4{0.f,0.f,0.f,0.f};

  // ---- prologue: issued order = gll(0), bvA(0), gll(1) ----
  GLL(0, 0);
  BVLOAD(bvA, 0);
  CFENCE();
  GLL(1, 1);

  // ---- main loop: 26 pairs, steps 0..51; buffers rotate cCur/cNxt/cThd ----
  int cCur = 0, cNxt = 1, cThd = 2;
  for (int p=0; p<26; ++p){
    const int s = 2*p;
    BARV(1);                       // waits gll(s)+bv(s); keeps gll(s+1) in flight
    MSTEP(cCur, bvA);
    BVLOAD(bvB, s+1);
    CFENCE();
    GLL(cThd, s+2);
    BARV(1);
    MSTEP(cNxt, bvB);
    BVLOAD(bvA, s+2);
    CFENCE();
    GLL(cCur, s+3);
    int t = cCur; cCur = cThd; cThd = cNxt; cNxt = t;
  }
  // ---- peeled iters 52, 53 ----
  BARV(1);                         // waits gll(52)+bv(52); keeps gll(53)
  MSTEP(cCur, bvA);
  BVLOAD(bvB, 53);
  BARV(0);                         // final drain: gll(53)+bv(53)
  MSTEP(cNxt, bvB);

  // ---- +conv_b, LN(256) across waves, relu -> t3 ----
  float sum[2][4], sq[2][4];
  #pragma unroll
  for (int mt=0;mt<2;++mt)
    #pragma unroll
    for (int r=0;r<4;++r){ sum[mt][r]=0.f; sq[mt][r]=0.f; }
  float biasv[4];
  #pragma unroll
  for (int nt=0;nt<4;++nt) biasv[nt] = cb[w*64+nt*16+lr];
  #pragma unroll
  for (int mt=0;mt<2;++mt)
    #pragma unroll
    for (int nt=0;nt<4;++nt)
      #pragma unroll
      for (int r=0;r<4;++r){
        float vv = acc1[mt][nt][r] + biasv[nt];
        acc1[mt][nt][r] = vv; sum[mt][r]+=vv; sq[mt][r]+=vv*vv;
      }
  #pragma unroll
  for (int m=1;m<16;m<<=1){
    #pragma unroll
    for (int mt=0;mt<2;++mt)
      #pragma unroll
      for (int r=0;r<4;++r){ sum[mt][r]+=__shfl_xor(sum[mt][r],m); sq[mt][r]+=__shfl_xor(sq[mt][r],m); }
  }
  if (lr==0){
    #pragma unroll
    for (int mt=0;mt<2;++mt)
      #pragma unroll
      for (int r=0;r<4;++r){
        const int row = mt*16+lh*4+r;
        ps[w][row]=sum[mt][r]; pq[w][row]=sq[mt][r];
      }
  }
  __syncthreads();
  float meanv[2][4], rstdv[2][4];
  #pragma unroll
  for (int mt=0;mt<2;++mt)
    #pragma unroll
    for (int r=0;r<4;++r){
      const int row = mt*16+lh*4+r;
      const float S = ps[0][row]+ps[1][row]+ps[2][row]+ps[3][row];
      const float Q = pq[0][row]+pq[1][row]+pq[2][row]+pq[3][row];
      const float mu = S*(1.f/Hn);
      meanv[mt][r] = mu;
      rstdv[mt][r] = rsqrtf(fmaxf(Q*(1.f/Hn)-mu*mu, 0.f) + 1e-12f);
    }
  #pragma unroll
  for (int nt=0;nt<4;++nt){
    const int c2 = w*64+nt*16+lr;
    const float nw = n2w[c2], nb = n2b[c2];
    #pragma unroll
    for (int mt=0;mt<2;++mt)
      #pragma unroll
      for (int r=0;r<4;++r){
        const int row = mt*16+lh*4+r;
        float t = (acc1[mt][nt][r]-meanv[mt][r])*rstdv[mt][r]*nw + nb;
        t3[(row*256+c2) ^ ((row&7)<<3)] = f2b(fmaxf(t,0.f));
      }
  }
  __syncthreads();

  // ---- GEMM2 (two 64-col halves): y[32x512] = t3 @ lin2_W^T (K=256) ----
  #pragma unroll
  for (int h=0; h<2; ++h){
    f32x4 acc2[2][4];
    #pragma unroll
    for (int i=0;i<2;++i)
      #pragma unroll
      for (int j=0;j<4;++j) acc2[i][j] = f32x4{0.f,0.f,0.f,0.f};
    for (int kk=0;kk<8;++kk){
      bf16x8 a[2];
      #pragma unroll
      for (int mt=0;mt<2;++mt){
        const int row = mt*16+lr;
        a[mt] = ld8(&t3[(row*256 + kk*32 + lh*8) ^ ((row&7)<<3)]);
      }
      #pragma unroll
      for (int nt=0;nt<4;++nt){
        bf16x8 bb = ld8(W2f + (size_t)(((w*8 + h*4 + nt)*8) + kk)*512 + l*8);
        #pragma unroll
        for (int mt=0;mt<2;++mt) acc2[mt][nt] = mfma16(a[mt], bb, acc2[mt][nt]);
      }
    }
    #pragma unroll
    for (int nt=0;nt<4;++nt){
      const int c2 = w*128 + h*64 + nt*16 + lr;
      const float bias = bl2[c2];
      #pragma unroll
      for (int mt=0;mt<2;++mt){
        #pragma unroll
        for (int r=0;r<4;++r){
          const int mg = m0 + mt*16 + lh*4 + r;
          if (mg < Nn){
            const size_t off = ((size_t)b*Nn + mg)*Cn + c2;
            out[off] = acc2[mt][nt][r] + bias + x[off];
          }
        }
      }
    }
  }
  #undef GLL
  #undef BVLOAD
  #undef MSTEP
}

extern "C" void kernel_launch(void* const* d_in, const int* in_sizes, int n_in,
                              void* d_out, int out_size, void* d_ws, size_t ws_size,
                              hipStream_t stream){
  const float* x    = (const float*)d_in[0];
  const float* adj  = (const float*)d_in[1];
  const float* prw  = (const float*)d_in[2];
  const float* prb  = (const float*)d_in[3];
  const float* W1   = (const float*)d_in[4];
  const float* b1   = (const float*)d_in[5];
  const float* n1w  = (const float*)d_in[6];
  const float* n1b  = (const float*)d_in[7];
  const float* Wc   = (const float*)d_in[8];
  const float* cbv  = (const float*)d_in[9];
  const float* n2w  = (const float*)d_in[10];
  const float* n2b  = (const float*)d_in[11];
  const float* W2   = (const float*)d_in[12];
  const float* bl2  = (const float*)d_in[13];

  u16* ws    = (u16*)d_ws;
  u16* W1f   = ws;                           // 131072 u16
  u16* WcTf  = ws + 131072;                  // 65536
  u16* W2f   = ws + 131072 + 65536;          // 131072
  u16* supT  = ws + 131072 + 65536 + 131072; // 32*16*54*512 u16 (~28.3 MB)

  k_prep<<<dim3(160), dim3(256), 0, stream>>>(W1, Wc, W2, W1f, WcTf, W2f);
  k_stageA<<<dim3(MTA,Bn), dim3(256), 0, stream>>>(x, prw, prb, W1f, b1, n1w, n1b, WcTf, supT);
  k_stageB<<<dim3(54*Bn), dim3(256), 0, stream>>>(adj, supT, cbv, n2w, n2b, W2f, bl2, x, (float*)d_out);
}

// Round 10
// 416.577 us; speedup vs baseline: 1.0228x; 1.0228x over previous
//
#include <hip/hip_runtime.h>
#include <stdint.h>

#define Bn 32
#define Nn 1723
#define Cn 512
#define Hn 256
#define MTA 54    // ceil(1723/32): stage-A tiles == supT sub-steps

typedef __bf16 bf16x8 __attribute__((ext_vector_type(8)));
typedef float f32x4 __attribute__((ext_vector_type(4)));
typedef unsigned short u16;

__device__ __forceinline__ u16 f2b(float f){
  union{float f; uint32_t i;} c; c.f=f; uint32_t u=c.i;
  u += 0x7fffu + ((u>>16)&1u);
  return (u16)(u>>16);
}
__device__ __forceinline__ bf16x8 ld8(const u16* p){
  union{ uint4 u; bf16x8 b; } c;
  c.u = *reinterpret_cast<const uint4*>(p);
  return c.b;
}
__device__ __forceinline__ f32x4 mfma16(bf16x8 a, bf16x8 b, f32x4 c){
  return __builtin_amdgcn_mfma_f32_16x16x32_bf16(a,b,c,0,0,0);
}
__device__ __forceinline__ bf16x8 cvt8(float4 a, float4 b){
  union{ uint32_t w[4]; bf16x8 v; } r;
  asm("v_cvt_pk_bf16_f32 %0, %1, %2" : "=v"(r.w[0]) : "v"(a.x), "v"(a.y));
  asm("v_cvt_pk_bf16_f32 %0, %1, %2" : "=v"(r.w[1]) : "v"(a.z), "v"(a.w));
  asm("v_cvt_pk_bf16_f32 %0, %1, %2" : "=v"(r.w[2]) : "v"(b.x), "v"(b.y));
  asm("v_cvt_pk_bf16_f32 %0, %1, %2" : "=v"(r.w[3]) : "v"(b.z), "v"(b.w));
  return r.v;
}
// counted-vmcnt barrier: keep N youngest VMEM ops in flight across the barrier
#define BARV(n) do{ asm volatile("s_waitcnt vmcnt(" #n ") lgkmcnt(0)" ::: "memory"); \
                    __builtin_amdgcn_s_barrier(); \
                    asm volatile("" ::: "memory"); }while(0)
#define CFENCE() asm volatile("" ::: "memory")
#define GLD_LDS16(gp, lp) \
  __builtin_amdgcn_global_load_lds((const __attribute__((address_space(1))) void*)(gp), \
                                   (__attribute__((address_space(3))) void*)(lp), 16, 0, 0)

// ---- kernel 0: weights -> bf16 MFMA-fragment-major (validated R5) ----
__global__ __launch_bounds__(256) void k_prep(
    const float* __restrict__ W1, const float* __restrict__ Wc, const float* __restrict__ W2,
    u16* __restrict__ W1f, u16* __restrict__ WcTf, u16* __restrict__ W2f)
{
  const int t = blockIdx.x*256 + threadIdx.x;
  const int lane = t & 63, unit = t >> 6;
  const int lr = lane & 15, lh = lane >> 4;
  const float* src; u16* dst; int K, tile, kk; bool tr = false;
  if (unit < 256){ tile = unit>>4; kk = unit&15; src = W1; dst = W1f; K = 512; }
  else if (unit < 384){ int u = unit-256; tile = u>>3; kk = u&7; src = Wc; dst = WcTf; K = 256; tr = true; }
  else { int u = unit-384; tile = u>>3; kk = u&7; src = W2; dst = W2f; K = 256; }
  const int row = tile*16 + lr;
  const int k0 = kk*32 + lh*8;
  union{u16 s[8]; uint4 u;} o;
  #pragma unroll
  for (int j=0;j<8;++j){
    float v = tr ? src[(size_t)(k0+j)*256 + row] : src[(size_t)row*K + k0 + j];
    o.s[j] = f2b(v);
  }
  *reinterpret_cast<uint4*>(dst + (size_t)(tile*(K/32)+kk)*512 + lane*8) = o.u;
}

// ---------------- stage A (validated; phantom vertices ZEROED in supT) ----------------
__global__ __launch_bounds__(256) void k_stageA(
    const float* __restrict__ x, const float* __restrict__ prw, const float* __restrict__ prb,
    const u16* __restrict__ W1f, const float* __restrict__ b1,
    const float* __restrict__ n1w, const float* __restrict__ n1b,
    const u16* __restrict__ WcTf, u16* __restrict__ supT)
{
  __shared__ u16 t1[32*512];
  __shared__ float ps[2][32], pq[2][32];
  u16* const t2 = t1;
  const int b = blockIdx.y;
  const int m0 = blockIdx.x*32;
  const int tid = threadIdx.x;
  const int w = tid>>6, l = tid&63, lr = l&15, lh = l>>4;
  const int wm = w>>1, wn = w&1;

  float pw[8], pb[8];
  #pragma unroll
  for (int j=0;j<8;++j){ pw[j]=prw[l*8+j]; pb[j]=prb[l*8+j]; }
  #pragma unroll
  for (int rr=0; rr<8; ++rr){
    const int rloc = w*8+rr;
    int rg = m0 + rloc; rg = rg < Nn ? rg : Nn-1;
    const float* src = x + ((size_t)b*Nn + rg)*Cn + l*8;
    float4 c0 = *reinterpret_cast<const float4*>(src);
    float4 c1 = *reinterpret_cast<const float4*>(src+4);
    float v[8] = {c0.x,c0.y,c0.z,c0.w,c1.x,c1.y,c1.z,c1.w};
    float s=0.f, q=0.f;
    #pragma unroll
    for (int j=0;j<8;++j){ s+=v[j]; q+=v[j]*v[j]; }
    #pragma unroll
    for (int m=1;m<64;m<<=1){ s += __shfl_xor(s,m); q += __shfl_xor(q,m); }
    const float mean = s*(1.f/Cn);
    const float rstd = rsqrtf(fmaxf(q*(1.f/Cn) - mean*mean, 0.f) + 1e-12f);
    union{uint4 u; u16 s[8];} ov;
    #pragma unroll
    for (int j=0;j<8;++j){
      float t = (v[j]-mean)*rstd*pw[j] + pb[j];
      ov.s[j] = f2b(fmaxf(t,0.f));
    }
    const int idx = (rloc*512 + l*8) ^ ((rloc&7)<<3);
    *reinterpret_cast<uint4*>(&t1[idx]) = ov.u;
  }
  __syncthreads();

  f32x4 acc[8];
  #pragma unroll
  for (int i=0;i<8;++i) acc[i] = f32x4{0.f,0.f,0.f,0.f};
  const int arow = wm*16 + lr;
  const int aswz = (arow&7)<<3;
  for (int kk=0; kk<16; ++kk){
    bf16x8 a = ld8(&t1[(arow*512 + kk*32 + lh*8) ^ aswz]);
    #pragma unroll
    for (int nt=0; nt<8; ++nt){
      bf16x8 bb = ld8(W1f + (size_t)(((wn*8+nt)*16 + kk))*512 + l*8);
      acc[nt] = mfma16(a, bb, acc[nt]);
    }
  }

  float sum[4]={0,0,0,0}, sq[4]={0,0,0,0};
  #pragma unroll
  for (int nt=0; nt<8; ++nt){
    const float bias = b1[wn*128+nt*16+lr];
    #pragma unroll
    for (int r=0;r<4;++r){
      float vv = acc[nt][r] + bias;
      acc[nt][r] = vv; sum[r]+=vv; sq[r]+=vv*vv;
    }
  }
  #pragma unroll
  for (int m=1;m<16;m<<=1){
    #pragma unroll
    for (int r=0;r<4;++r){ sum[r]+=__shfl_xor(sum[r],m); sq[r]+=__shfl_xor(sq[r],m); }
  }
  if (lr==0){
    #pragma unroll
    for (int r=0;r<4;++r){
      const int row = wm*16 + lh*4 + r;
      ps[wn][row]=sum[r]; pq[wn][row]=sq[r];
    }
  }
  __syncthreads();
  float mean[4], rstd[4];
  #pragma unroll
  for (int r=0;r<4;++r){
    const int row = wm*16 + lh*4 + r;
    const float S = ps[0][row]+ps[1][row];
    const float Q = pq[0][row]+pq[1][row];
    const float mu = S*(1.f/Hn);
    mean[r] = mu;
    rstd[r] = rsqrtf(fmaxf(Q*(1.f/Hn) - mu*mu, 0.f) + 1e-12f);
  }
  #pragma unroll
  for (int nt=0; nt<8; ++nt){
    const int col = wn*128+nt*16+lr;
    const float nw = n1w[col], nb = n1b[col];
    #pragma unroll
    for (int r=0;r<4;++r){
      const int row = wm*16 + lh*4 + r;
      float t = (acc[nt][r]-mean[r])*rstd[r]*nw + nb;
      t2[(row*256 + col) ^ ((row&7)<<3)] = f2b(fmaxf(t,0.f));
    }
  }
  __syncthreads();

  f32x4 acc2[8];
  #pragma unroll
  for (int i=0;i<8;++i) acc2[i] = f32x4{0.f,0.f,0.f,0.f};
  for (int kk=0; kk<8; ++kk){
    bf16x8 a = ld8(&t2[(arow*256 + kk*32 + lh*8) ^ aswz]);
    #pragma unroll
    for (int nt=0; nt<8; ++nt){
      bf16x8 bb = ld8(WcTf + (size_t)(((wn*8+nt)*8 + kk))*512 + l*8);
      acc2[nt] = mfma16(a, bb, acc2[nt]);
    }
  }

  const int off512 = (wm*2 + (lh>>1))*128 + lr*8 + (lh&1)*4;
  const int vbase = m0 + wm*16 + lh*4;
  #pragma unroll
  for (int nt=0; nt<8; ++nt){
    const int htile = wn*8 + nt;
    const size_t base = ((size_t)(b*16 + htile)*MTA + blockIdx.x)*512 + off512;
    ushort4 o;
    o.x = (vbase+0 < Nn) ? f2b(acc2[nt][0]) : (u16)0;
    o.y = (vbase+1 < Nn) ? f2b(acc2[nt][1]) : (u16)0;
    o.z = (vbase+2 < Nn) ? f2b(acc2[nt][2]) : (u16)0;
    o.w = (vbase+3 < Nn) ? f2b(acc2[nt][3]) : (u16)0;
    *reinterpret_cast<ushort4*>(supT + base) = o;
  }
}

// ---------------- stage B: 6-buffer gll ring + 3-set bv prefetch, counted vmcnt(6) ----------------
// grid 1728 = 8 XCD x (4 b x 54 tiles of 32 rows). 4 waves/block.
// Swizzle: 4-float blocks XOR (row&7) — balanced 8 lanes/bank-group per ds_read_b128.
__global__ __launch_bounds__(256) void k_stageB(
    const float* __restrict__ adj, const u16* __restrict__ supT,
    const float* __restrict__ cb, const float* __restrict__ n2w, const float* __restrict__ n2b,
    const u16* __restrict__ W2f, const float* __restrict__ bl2,
    const float* __restrict__ x, float* __restrict__ out)
{
  __shared__ float smf[6*1024];      // 24 KB adj ring; aliased by t3 after K-loop
  __shared__ float ps[4][32], pq[4][32];
  u16* const t3 = (u16*)smf;
  const int bid = blockIdx.x;
  const int xcd = bid & 7, idx = bid >> 3;
  const int b = xcd*4 + (idx & 3);          // 4 consecutive b per XCD (supT L2-resident)
  const int m0 = (idx >> 2) * 32;
  const int tid = threadIdx.x, w = tid>>6, l = tid&63, lr = l&15, lh = l>>4;

  const float* adjb = adj + (size_t)b*Nn*Nn;
  const u16* supb = supT + (size_t)b*16*MTA*512;
  const float* gmax = adj + ((size_t)Bn*Nn*Nn - 4);

  // gll source geometry: lane -> row 8w+(l>>3), 16B chunk pch; source col-block = pch ^ (row&7)
  int grow = m0 + 8*w + (l>>3); grow = grow < Nn ? grow : Nn-1;
  const int pch = l&7;
  const float* gbase = adjb + (size_t)grow*Nn + ((pch ^ (grow&7))<<2);
  float* const abase = smf + w*256;         // wave-uniform dest (rows 8w..8w+7)

  // MFMA-read float offsets (4-float-block swizzle): off^4 gives the partner block
  const int ar0 = lr, ar1 = 16+lr;
  const int off0 = ar0*32 + (((lh*2) ^ (ar0&7))<<2);
  const int off1 = ar1*32 + (((lh*2) ^ (ar1&7))<<2);

  bf16x8 bvS0[4], bvS1[4], bvS2[4];
  f32x4 acc1[2][4];
  #pragma unroll
  for (int i=0;i<2;++i)
    #pragma unroll
    for (int j=0;j<4;++j) acc1[i][j] = f32x4{0.f,0.f,0.f,0.f};

  #define GLLW(c, s4) do{                                                \
    const float* gp = gbase + (size_t)(s4)*32;                           \
    if (gp > gmax) gp = gmax;                                            \
    GLD_LDS16(gp, abase + (c)*1024);                                     \
  }while(0)

  #define BVL(bvr, s) do{                                                \
    const int sb_ = (s) > 53 ? 53 : (s);                                 \
    _Pragma("unroll")                                                    \
    for (int nt=0;nt<4;++nt)                                             \
      bvr[nt] = ld8(supb + (size_t)((w*4+nt)*MTA + sb_)*512 + l*8);      \
  }while(0)

  #define MSTEP(c, bvr) do{                                              \
    {                                                                    \
      float4 v0 = *reinterpret_cast<const float4*>(smf + (c)*1024 + off0); \
      float4 v1 = *reinterpret_cast<const float4*>(smf + (c)*1024 + (off0^4)); \
      bf16x8 af = cvt8(v0, v1);                                          \
      _Pragma("unroll")                                                  \
      for (int nt=0;nt<4;++nt) acc1[0][nt] = mfma16(af, bvr[nt], acc1[0][nt]); \
    }{                                                                   \
      float4 v0 = *reinterpret_cast<const float4*>(smf + (c)*1024 + off1); \
      float4 v1 = *reinterpret_cast<const float4*>(smf + (c)*1024 + (off1^4)); \
      bf16x8 af = cvt8(v0, v1);                                          \
      _Pragma("unroll")                                                  \
      for (int nt=0;nt<4;++nt) acc1[1][nt] = mfma16(af, bvr[nt], acc1[1][nt]); \
    }                                                                    \
  }while(0)

  #define PHASE(cj, gj, bvcur, bvfill) do{                               \
    BARV(6);                                                             \
    MSTEP(cj, bvcur);                                                    \
    BVL(bvfill, s+2);                                                    \
    CFENCE();                                                            \
    GLLW(gj, s+4);                                                       \
    ++s;                                                                 \
  }while(0)

  // ---- prologue: FIFO = [gll0, gll1, bv0, gll2, bv1, gll3] ----
  GLLW(0, 0);
  GLLW(1, 1);
  CFENCE();
  BVL(bvS0, 0);
  CFENCE();
  GLLW(2, 2);
  CFENCE();
  BVL(bvS1, 1);
  CFENCE();
  GLLW(3, 3);

  // ---- main loop: 9 x 6 statically-indexed phases (steps 0..53) ----
  int s = 0;
  for (int blk=0; blk<9; ++blk){
    PHASE(0, 4, bvS0, bvS2);
    PHASE(1, 5, bvS1, bvS0);
    PHASE(2, 0, bvS2, bvS1);
    PHASE(3, 1, bvS0, bvS2);
    PHASE(4, 2, bvS1, bvS0);
    PHASE(5, 3, bvS2, bvS1);
  }
  // final drain (also separates atile lifetime from t3 alias)
  asm volatile("s_waitcnt vmcnt(0) lgkmcnt(0)" ::: "memory");
  __builtin_amdgcn_s_barrier();
  CFENCE();

  // ---- +conv_b, LN(256) across waves, relu -> t3 ----
  float sum[2][4], sq[2][4];
  #pragma unroll
  for (int mt=0;mt<2;++mt)
    #pragma unroll
    for (int r=0;r<4;++r){ sum[mt][r]=0.f; sq[mt][r]=0.f; }
  float biasv[4];
  #pragma unroll
  for (int nt=0;nt<4;++nt) biasv[nt] = cb[w*64+nt*16+lr];
  #pragma unroll
  for (int mt=0;mt<2;++mt)
    #pragma unroll
    for (int nt=0;nt<4;++nt)
      #pragma unroll
      for (int r=0;r<4;++r){
        float vv = acc1[mt][nt][r] + biasv[nt];
        acc1[mt][nt][r] = vv; sum[mt][r]+=vv; sq[mt][r]+=vv*vv;
      }
  #pragma unroll
  for (int m=1;m<16;m<<=1){
    #pragma unroll
    for (int mt=0;mt<2;++mt)
      #pragma unroll
      for (int r=0;r<4;++r){ sum[mt][r]+=__shfl_xor(sum[mt][r],m); sq[mt][r]+=__shfl_xor(sq[mt][r],m); }
  }
  if (lr==0){
    #pragma unroll
    for (int mt=0;mt<2;++mt)
      #pragma unroll
      for (int r=0;r<4;++r){
        const int row = mt*16+lh*4+r;
        ps[w][row]=sum[mt][r]; pq[w][row]=sq[mt][r];
      }
  }
  __syncthreads();
  float meanv[2][4], rstdv[2][4];
  #pragma unroll
  for (int mt=0;mt<2;++mt)
    #pragma unroll
    for (int r=0;r<4;++r){
      const int row = mt*16+lh*4+r;
      const float S = ps[0][row]+ps[1][row]+ps[2][row]+ps[3][row];
      const float Q = pq[0][row]+pq[1][row]+pq[2][row]+pq[3][row];
      const float mu = S*(1.f/Hn);
      meanv[mt][r] = mu;
      rstdv[mt][r] = rsqrtf(fmaxf(Q*(1.f/Hn)-mu*mu, 0.f) + 1e-12f);
    }
  #pragma unroll
  for (int nt=0;nt<4;++nt){
    const int c2 = w*64+nt*16+lr;
    const float nw = n2w[c2], nb = n2b[c2];
    #pragma unroll
    for (int mt=0;mt<2;++mt)
      #pragma unroll
      for (int r=0;r<4;++r){
        const int row = mt*16+lh*4+r;
        float t = (acc1[mt][nt][r]-meanv[mt][r])*rstdv[mt][r]*nw + nb;
        t3[(row*256+c2) ^ ((row&7)<<3)] = f2b(fmaxf(t,0.f));
      }
  }
  __syncthreads();

  // ---- GEMM2 (two 64-col halves): y[32x512] = t3 @ lin2_W^T (K=256) ----
  #pragma unroll
  for (int h=0; h<2; ++h){
    f32x4 acc2[2][4];
    #pragma unroll
    for (int i=0;i<2;++i)
      #pragma unroll
      for (int j=0;j<4;++j) acc2[i][j] = f32x4{0.f,0.f,0.f,0.f};
    for (int kk=0;kk<8;++kk){
      bf16x8 a[2];
      #pragma unroll
      for (int mt=0;mt<2;++mt){
        const int row = mt*16+lr;
        a[mt] = ld8(&t3[(row*256 + kk*32 + lh*8) ^ ((row&7)<<3)]);
      }
      #pragma unroll
      for (int nt=0;nt<4;++nt){
        bf16x8 bb = ld8(W2f + (size_t)(((w*8 + h*4 + nt)*8) + kk)*512 + l*8);
        #pragma unroll
        for (int mt=0;mt<2;++mt) acc2[mt][nt] = mfma16(a[mt], bb, acc2[mt][nt]);
      }
    }
    #pragma unroll
    for (int nt=0;nt<4;++nt){
      const int c2 = w*128 + h*64 + nt*16 + lr;
      const float bias = bl2[c2];
      #pragma unroll
      for (int mt=0;mt<2;++mt){
        #pragma unroll
        for (int r=0;r<4;++r){
          const int mg = m0 + mt*16 + lh*4 + r;
          if (mg < Nn){
            const size_t off = ((size_t)b*Nn + mg)*Cn + c2;
            out[off] = acc2[mt][nt][r] + bias + x[off];
          }
        }
      }
    }
  }
  #undef GLLW
  #undef BVL
  #undef MSTEP
  #undef PHASE
}

extern "C" void kernel_launch(void* const* d_in, const int* in_sizes, int n_in,
                              void* d_out, int out_size, void* d_ws, size_t ws_size,
                              hipStream_t stream){
  const float* x    = (const float*)d_in[0];
  const float* adj  = (const float*)d_in[1];
  const float* prw  = (const float*)d_in[2];
  const float* prb  = (const float*)d_in[3];
  const float* W1   = (const float*)d_in[4];
  const float* b1   = (const float*)d_in[5];
  const float* n1w  = (const float*)d_in[6];
  const float* n1b  = (const float*)d_in[7];
  const float* Wc   = (const float*)d_in[8];
  const float* cbv  = (const float*)d_in[9];
  const float* n2w  = (const float*)d_in[10];
  const float* n2b  = (const float*)d_in[11];
  const float* W2   = (const float*)d_in[12];
  const float* bl2  = (const float*)d_in[13];

  u16* ws    = (u16*)d_ws;
  u16* W1f   = ws;                           // 131072 u16
  u16* WcTf  = ws + 131072;                  // 65536
  u16* W2f   = ws + 131072 + 65536;          // 131072
  u16* supT  = ws + 131072 + 65536 + 131072; // 32*16*54*512 u16 (~28.3 MB)

  k_prep<<<dim3(160), dim3(256), 0, stream>>>(W1, Wc, W2, W1f, WcTf, W2f);
  k_stageA<<<dim3(MTA,Bn), dim3(256), 0, stream>>>(x, prw, prb, W1f, b1, n1w, n1b, WcTf, supT);
  k_stageB<<<dim3(54*Bn), dim3(256), 0, stream>>>(adj, supT, cbv, n2w, n2b, W2f, bl2, x, (float*)d_out);
}

// Round 11
// 377.206 us; speedup vs baseline: 1.1296x; 1.1044x over previous
//
#include <hip/hip_runtime.h>
#include <stdint.h>

#define Bn 32
#define Nn 1723
#define Cn 512
#define Hn 256
#define MTA 54    // ceil(1723/32): stage-A tiles == supT 32-col sub-steps

typedef __bf16 bf16x8 __attribute__((ext_vector_type(8)));
typedef float f32x4 __attribute__((ext_vector_type(4)));
typedef unsigned short u16;

__device__ __forceinline__ u16 f2b(float f){
  union{float f; uint32_t i;} c; c.f=f; uint32_t u=c.i;
  u += 0x7fffu + ((u>>16)&1u);
  return (u16)(u>>16);
}
__device__ __forceinline__ bf16x8 ld8(const u16* p){
  union{ uint4 u; bf16x8 b; } c;
  c.u = *reinterpret_cast<const uint4*>(p);
  return c.b;
}
__device__ __forceinline__ f32x4 mfma16(bf16x8 a, bf16x8 b, f32x4 c){
  return __builtin_amdgcn_mfma_f32_16x16x32_bf16(a,b,c,0,0,0);
}
__device__ __forceinline__ bf16x8 cvt8(float4 a, float4 b){
  union{ uint32_t w[4]; bf16x8 v; } r;
  asm("v_cvt_pk_bf16_f32 %0, %1, %2" : "=v"(r.w[0]) : "v"(a.x), "v"(a.y));
  asm("v_cvt_pk_bf16_f32 %0, %1, %2" : "=v"(r.w[1]) : "v"(a.z), "v"(a.w));
  asm("v_cvt_pk_bf16_f32 %0, %1, %2" : "=v"(r.w[2]) : "v"(b.x), "v"(b.y));
  asm("v_cvt_pk_bf16_f32 %0, %1, %2" : "=v"(r.w[3]) : "v"(b.z), "v"(b.w));
  return r.v;
}
#define VMW(n)  asm volatile("s_waitcnt vmcnt(" #n ")" ::: "memory")
#define CFENCE() asm volatile("" ::: "memory")
#define GLD_LDS16(gp, lp) \
  __builtin_amdgcn_global_load_lds((const __attribute__((address_space(1))) void*)(gp), \
                                   (__attribute__((address_space(3))) void*)(lp), 16, 0, 0)

// ---- kernel 0: weights -> bf16 MFMA-fragment-major (validated R5) ----
__global__ __launch_bounds__(256) void k_prep(
    const float* __restrict__ W1, const float* __restrict__ Wc, const float* __restrict__ W2,
    u16* __restrict__ W1f, u16* __restrict__ WcTf, u16* __restrict__ W2f)
{
  const int t = blockIdx.x*256 + threadIdx.x;
  const int lane = t & 63, unit = t >> 6;
  const int lr = lane & 15, lh = lane >> 4;
  const float* src; u16* dst; int K, tile, kk; bool tr = false;
  if (unit < 256){ tile = unit>>4; kk = unit&15; src = W1; dst = W1f; K = 512; }
  else if (unit < 384){ int u = unit-256; tile = u>>3; kk = u&7; src = Wc; dst = WcTf; K = 256; tr = true; }
  else { int u = unit-384; tile = u>>3; kk = u&7; src = W2; dst = W2f; K = 256; }
  const int row = tile*16 + lr;
  const int k0 = kk*32 + lh*8;
  union{u16 s[8]; uint4 u;} o;
  #pragma unroll
  for (int j=0;j<8;++j){
    float v = tr ? src[(size_t)(k0+j)*256 + row] : src[(size_t)row*K + k0 + j];
    o.s[j] = f2b(v);
  }
  *reinterpret_cast<uint4*>(dst + (size_t)(tile*(K/32)+kk)*512 + lane*8) = o.u;
}

// ---------------- stage A (validated; phantom vertices ZEROED in supT) ----------------
__global__ __launch_bounds__(256) void k_stageA(
    const float* __restrict__ x, const float* __restrict__ prw, const float* __restrict__ prb,
    const u16* __restrict__ W1f, const float* __restrict__ b1,
    const float* __restrict__ n1w, const float* __restrict__ n1b,
    const u16* __restrict__ WcTf, u16* __restrict__ supT)
{
  __shared__ u16 t1[32*512];
  __shared__ float ps[2][32], pq[2][32];
  u16* const t2 = t1;
  const int b = blockIdx.y;
  const int m0 = blockIdx.x*32;
  const int tid = threadIdx.x;
  const int w = tid>>6, l = tid&63, lr = l&15, lh = l>>4;
  const int wm = w>>1, wn = w&1;

  float pw[8], pb[8];
  #pragma unroll
  for (int j=0;j<8;++j){ pw[j]=prw[l*8+j]; pb[j]=prb[l*8+j]; }
  #pragma unroll
  for (int rr=0; rr<8; ++rr){
    const int rloc = w*8+rr;
    int rg = m0 + rloc; rg = rg < Nn ? rg : Nn-1;
    const float* src = x + ((size_t)b*Nn + rg)*Cn + l*8;
    float4 c0 = *reinterpret_cast<const float4*>(src);
    float4 c1 = *reinterpret_cast<const float4*>(src+4);
    float v[8] = {c0.x,c0.y,c0.z,c0.w,c1.x,c1.y,c1.z,c1.w};
    float s=0.f, q=0.f;
    #pragma unroll
    for (int j=0;j<8;++j){ s+=v[j]; q+=v[j]*v[j]; }
    #pragma unroll
    for (int m=1;m<64;m<<=1){ s += __shfl_xor(s,m); q += __shfl_xor(q,m); }
    const float mean = s*(1.f/Cn);
    const float rstd = rsqrtf(fmaxf(q*(1.f/Cn) - mean*mean, 0.f) + 1e-12f);
    union{uint4 u; u16 s[8];} ov;
    #pragma unroll
    for (int j=0;j<8;++j){
      float t = (v[j]-mean)*rstd*pw[j] + pb[j];
      ov.s[j] = f2b(fmaxf(t,0.f));
    }
    const int idx = (rloc*512 + l*8) ^ ((rloc&7)<<3);
    *reinterpret_cast<uint4*>(&t1[idx]) = ov.u;
  }
  __syncthreads();

  f32x4 acc[8];
  #pragma unroll
  for (int i=0;i<8;++i) acc[i] = f32x4{0.f,0.f,0.f,0.f};
  const int arow = wm*16 + lr;
  const int aswz = (arow&7)<<3;
  for (int kk=0; kk<16; ++kk){
    bf16x8 a = ld8(&t1[(arow*512 + kk*32 + lh*8) ^ aswz]);
    #pragma unroll
    for (int nt=0; nt<8; ++nt){
      bf16x8 bb = ld8(W1f + (size_t)(((wn*8+nt)*16 + kk))*512 + l*8);
      acc[nt] = mfma16(a, bb, acc[nt]);
    }
  }

  float sum[4]={0,0,0,0}, sq[4]={0,0,0,0};
  #pragma unroll
  for (int nt=0; nt<8; ++nt){
    const float bias = b1[wn*128+nt*16+lr];
    #pragma unroll
    for (int r=0;r<4;++r){
      float vv = acc[nt][r] + bias;
      acc[nt][r] = vv; sum[r]+=vv; sq[r]+=vv*vv;
    }
  }
  #pragma unroll
  for (int m=1;m<16;m<<=1){
    #pragma unroll
    for (int r=0;r<4;++r){ sum[r]+=__shfl_xor(sum[r],m); sq[r]+=__shfl_xor(sq[r],m); }
  }
  if (lr==0){
    #pragma unroll
    for (int r=0;r<4;++r){
      const int row = wm*16 + lh*4 + r;
      ps[wn][row]=sum[r]; pq[wn][row]=sq[r];
    }
  }
  __syncthreads();
  float mean[4], rstd[4];
  #pragma unroll
  for (int r=0;r<4;++r){
    const int row = wm*16 + lh*4 + r;
    const float S = ps[0][row]+ps[1][row];
    const float Q = pq[0][row]+pq[1][row];
    const float mu = S*(1.f/Hn);
    mean[r] = mu;
    rstd[r] = rsqrtf(fmaxf(Q*(1.f/Hn) - mu*mu, 0.f) + 1e-12f);
  }
  #pragma unroll
  for (int nt=0; nt<8; ++nt){
    const int col = wn*128+nt*16+lr;
    const float nw = n1w[col], nb = n1b[col];
    #pragma unroll
    for (int r=0;r<4;++r){
      const int row = wm*16 + lh*4 + r;
      float t = (acc[nt][r]-mean[r])*rstd[r]*nw + nb;
      t2[(row*256 + col) ^ ((row&7)<<3)] = f2b(fmaxf(t,0.f));
    }
  }
  __syncthreads();

  f32x4 acc2[8];
  #pragma unroll
  for (int i=0;i<8;++i) acc2[i] = f32x4{0.f,0.f,0.f,0.f};
  for (int kk=0; kk<8; ++kk){
    bf16x8 a = ld8(&t2[(arow*256 + kk*32 + lh*8) ^ aswz]);
    #pragma unroll
    for (int nt=0; nt<8; ++nt){
      bf16x8 bb = ld8(WcTf + (size_t)(((wn*8+nt)*8 + kk))*512 + l*8);
      acc2[nt] = mfma16(a, bb, acc2[nt]);
    }
  }

  const int off512 = (wm*2 + (lh>>1))*128 + lr*8 + (lh&1)*4;
  const int vbase = m0 + wm*16 + lh*4;
  #pragma unroll
  for (int nt=0; nt<8; ++nt){
    const int htile = wn*8 + nt;
    const size_t base = ((size_t)(b*16 + htile)*MTA + blockIdx.x)*512 + off512;
    ushort4 o;
    o.x = (vbase+0 < Nn) ? f2b(acc2[nt][0]) : (u16)0;
    o.y = (vbase+1 < Nn) ? f2b(acc2[nt][1]) : (u16)0;
    o.z = (vbase+2 < Nn) ? f2b(acc2[nt][2]) : (u16)0;
    o.w = (vbase+3 < Nn) ? f2b(acc2[nt][3]) : (u16)0;
    *reinterpret_cast<ushort4*>(supT + base) = o;
  }
}

// ---------------- stage B: K-step-128 row-contiguous gll streaming ----------------
// grid 1728 = 8 XCD x (4 b x 54 tiles of 32 rows). 4 waves/block.
// Each gll = 2 rows x 512B CONTIGUOUS; rows stream sequentially across 14 steps.
// FIFO (verified): waits vmcnt 4/4/4/8 per step, queue <= 12, never drain-0 in loop.
__global__ __launch_bounds__(256) void k_stageB(
    const float* __restrict__ adj, const u16* __restrict__ supT,
    const float* __restrict__ cb, const float* __restrict__ n2w, const float* __restrict__ n2b,
    const u16* __restrict__ W2f, const float* __restrict__ bl2,
    const float* __restrict__ x, float* __restrict__ out)
{
  __shared__ float abuf[2][4096];    // 32 KB: 2 bufs x 32 rows x 128 f32, 4-float-block swizzle
  __shared__ float ps[4][32], pq[4][32];
  u16* const t3 = (u16*)&abuf[0][0]; // 16 KB alias after K-loop
  const int bid = blockIdx.x;
  const int xcd = bid & 7, idx = bid >> 3;
  const int b = xcd*4 + (idx & 3);          // 4 consecutive b per XCD
  const int m0 = (idx >> 2) * 32;
  const int tid = threadIdx.x, w = tid>>6, l = tid&63, lr = l&15, lh = l>>4;

  const float* adjb = adj + (size_t)b*Nn*Nn;
  const u16* supb = supT + (size_t)b*16*MTA*512;

  // gll source pointers: gll g covers local rows 8w+2g, 8w+2g+1 (512B each, contiguous)
  const float *gb0, *gb1, *gb2, *gb3;
  {
    const int sb = l & 31;
    #define MKGB(g, dst) { int rl = 8*w + 2*(g) + (l>>5); int rg = m0 + rl; \
                           if (rg > Nn-1) rg = Nn-1; \
                           dst = adjb + (size_t)rg*Nn + ((sb ^ (rl&7))<<2); }
    MKGB(0, gb0) MKGB(1, gb1) MKGB(2, gb2) MKGB(3, gb3)
    #undef MKGB
  }

  bf16x8 bvS0[4], bvS1[4];
  f32x4 acc1[2][4];
  #pragma unroll
  for (int i=0;i<2;++i)
    #pragma unroll
    for (int j=0;j<4;++j) acc1[i][j] = f32x4{0.f,0.f,0.f,0.f};

  #define GISSUE(buf, s) do{                                             \
    GLD_LDS16(gb0 + (size_t)(s)*128, &abuf[buf][(8*w+0)*128]);           \
    GLD_LDS16(gb1 + (size_t)(s)*128, &abuf[buf][(8*w+2)*128]);           \
    GLD_LDS16(gb2 + (size_t)(s)*128, &abuf[buf][(8*w+4)*128]);           \
    GLD_LDS16(gb3 + (size_t)(s)*128, &abuf[buf][(8*w+6)*128]);           \
  }while(0)

  #define BVL(set, i32) do{                                              \
    _Pragma("unroll")                                                    \
    for (int nt=0;nt<4;++nt)                                             \
      set[nt] = ld8(supb + (size_t)((w*4+nt)*MTA + (i32))*512 + l*8);    \
  }while(0)

  #define MSUB(buf, kk, set) do{                                         \
    _Pragma("unroll")                                                    \
    for (int mt=0;mt<2;++mt){                                            \
      const int row = mt*16 + lr;                                        \
      const int o0 = row*128 + ((((kk)*8 + lh*2) ^ (row&7))<<2);         \
      float4 v0 = *reinterpret_cast<const float4*>(&abuf[buf][o0]);      \
      float4 v1 = *reinterpret_cast<const float4*>(&abuf[buf][o0^4]);    \
      bf16x8 af = cvt8(v0, v1);                                          \
      _Pragma("unroll")                                                  \
      for (int nt=0;nt<4;++nt) acc1[mt][nt] = mfma16(af, set[nt], acc1[mt][nt]); \
    }                                                                    \
  }while(0)

  // ---- prologue: FIFO = [G(0), B(0,0), B(0,1)] ----
  GISSUE(0, 0); CFENCE();
  BVL(bvS0, 0); CFENCE();
  BVL(bvS1, 1); CFENCE();

  // ---- 13 uniform steps (s=0..12); step s reads buf s&1, consumes B(s,0..3)=idx 4s..4s+3 ----
  #pragma unroll 1
  for (int s=0; s<13; ++s){
    const int buf = s & 1;
    VMW(4); __builtin_amdgcn_s_barrier(); CFENCE();   // drains G(s)+B(s,0), keeps B(s,1)
    MSUB(buf, 0, bvS0);  BVL(bvS0, 4*s+2); CFENCE();
    VMW(4);                                           // drains B(s,1), keeps B(s,2)
    MSUB(buf, 1, bvS1);  BVL(bvS1, 4*s+3); CFENCE();
    VMW(4);                                           // drains B(s,2), keeps B(s,3)
    MSUB(buf, 2, bvS0);  GISSUE(buf^1, s+1); CFENCE(); BVL(bvS0, 4*s+4); CFENCE();
    VMW(8);                                           // drains B(s,3), keeps G(s+1)+B(s+1,0)
    MSUB(buf, 3, bvS1);  BVL(bvS1, 4*s+5); CFENCE();
  }
  // ---- tail step 13 (k 1664..1727, subs 0..1 only; buf 1) ----
  VMW(4); __builtin_amdgcn_s_barrier(); CFENCE();     // drains G(13)+B(13,0)
  MSUB(1, 0, bvS0);
  VMW(0);
  MSUB(1, 1, bvS1);
  asm volatile("s_waitcnt vmcnt(0) lgkmcnt(0)" ::: "memory");
  __builtin_amdgcn_s_barrier(); CFENCE();             // atile lifetime over (t3 alias safe)

  // ---- +conv_b, LN(256) across waves, relu -> t3 ----
  float sum[2][4], sq[2][4];
  #pragma unroll
  for (int mt=0;mt<2;++mt)
    #pragma unroll
    for (int r=0;r<4;++r){ sum[mt][r]=0.f; sq[mt][r]=0.f; }
  float biasv[4];
  #pragma unroll
  for (int nt=0;nt<4;++nt) biasv[nt] = cb[w*64+nt*16+lr];
  #pragma unroll
  for (int mt=0;mt<2;++mt)
    #pragma unroll
    for (int nt=0;nt<4;++nt)
      #pragma unroll
      for (int r=0;r<4;++r){
        float vv = acc1[mt][nt][r] + biasv[nt];
        acc1[mt][nt][r] = vv; sum[mt][r]+=vv; sq[mt][r]+=vv*vv;
      }
  #pragma unroll
  for (int m=1;m<16;m<<=1){
    #pragma unroll
    for (int mt=0;mt<2;++mt)
      #pragma unroll
      for (int r=0;r<4;++r){ sum[mt][r]+=__shfl_xor(sum[mt][r],m); sq[mt][r]+=__shfl_xor(sq[mt][r],m); }
  }
  if (lr==0){
    #pragma unroll
    for (int mt=0;mt<2;++mt)
      #pragma unroll
      for (int r=0;r<4;++r){
        const int row = mt*16+lh*4+r;
        ps[w][row]=sum[mt][r]; pq[w][row]=sq[mt][r];
      }
  }
  __syncthreads();
  float meanv[2][4], rstdv[2][4];
  #pragma unroll
  for (int mt=0;mt<2;++mt)
    #pragma unroll
    for (int r=0;r<4;++r){
      const int row = mt*16+lh*4+r;
      const float S = ps[0][row]+ps[1][row]+ps[2][row]+ps[3][row];
      const float Q = pq[0][row]+pq[1][row]+pq[2][row]+pq[3][row];
      const float mu = S*(1.f/Hn);
      meanv[mt][r] = mu;
      rstdv[mt][r] = rsqrtf(fmaxf(Q*(1.f/Hn)-mu*mu, 0.f) + 1e-12f);
    }
  #pragma unroll
  for (int nt=0;nt<4;++nt){
    const int c2 = w*64+nt*16+lr;
    const float nw = n2w[c2], nb = n2b[c2];
    #pragma unroll
    for (int mt=0;mt<2;++mt)
      #pragma unroll
      for (int r=0;r<4;++r){
        const int row = mt*16+lh*4+r;
        float t = (acc1[mt][nt][r]-meanv[mt][r])*rstdv[mt][r]*nw + nb;
        t3[(row*256+c2) ^ ((row&7)<<3)] = f2b(fmaxf(t,0.f));
      }
  }
  __syncthreads();

  // ---- GEMM2 (two 64-col halves): y[32x512] = t3 @ lin2_W^T (K=256) ----
  #pragma unroll
  for (int h=0; h<2; ++h){
    f32x4 acc2[2][4];
    #pragma unroll
    for (int i=0;i<2;++i)
      #pragma unroll
      for (int j=0;j<4;++j) acc2[i][j] = f32x4{0.f,0.f,0.f,0.f};
    for (int kk=0;kk<8;++kk){
      bf16x8 a[2];
      #pragma unroll
      for (int mt=0;mt<2;++mt){
        const int row = mt*16+lr;
        a[mt] = ld8(&t3[(row*256 + kk*32 + lh*8) ^ ((row&7)<<3)]);
      }
      #pragma unroll
      for (int nt=0;nt<4;++nt){
        bf16x8 bb = ld8(W2f + (size_t)(((w*8 + h*4 + nt)*8) + kk)*512 + l*8);
        #pragma unroll
        for (int mt=0;mt<2;++mt) acc2[mt][nt] = mfma16(a[mt], bb, acc2[mt][nt]);
      }
    }
    #pragma unroll
    for (int nt=0;nt<4;++nt){
      const int c2 = w*128 + h*64 + nt*16 + lr;
      const float bias = bl2[c2];
      #pragma unroll
      for (int mt=0;mt<2;++mt){
        #pragma unroll
        for (int r=0;r<4;++r){
          const int mg = m0 + mt*16 + lh*4 + r;
          if (mg < Nn){
            const size_t off = ((size_t)b*Nn + mg)*Cn + c2;
            out[off] = acc2[mt][nt][r] + bias + x[off];
          }
        }
      }
    }
  }
  #undef GISSUE
  #undef BVL
  #undef MSUB
}

extern "C" void kernel_launch(void* const* d_in, const int* in_sizes, int n_in,
                              void* d_out, int out_size, void* d_ws, size_t ws_size,
                              hipStream_t stream){
  const float* x    = (const float*)d_in[0];
  const float* adj  = (const float*)d_in[1];
  const float* prw  = (const float*)d_in[2];
  const float* prb  = (const float*)d_in[3];
  const float* W1   = (const float*)d_in[4];
  const float* b1   = (const float*)d_in[5];
  const float* n1w  = (const float*)d_in[6];
  const float* n1b  = (const float*)d_in[7];
  const float* Wc   = (const float*)d_in[8];
  const float* cbv  = (const float*)d_in[9];
  const float* n2w  = (const float*)d_in[10];
  const float* n2b  = (const float*)d_in[11];
  const float* W2   = (const float*)d_in[12];
  const float* bl2  = (const float*)d_in[13];

  u16* ws    = (u16*)d_ws;
  u16* W1f   = ws;                           // 131072 u16
  u16* WcTf  = ws + 131072;                  // 65536
  u16* W2f   = ws + 131072 + 65536;          // 131072
  u16* supT  = ws + 131072 + 65536 + 131072; // 32*16*54*512 u16 (~28.3 MB)

  k_prep<<<dim3(160), dim3(256), 0, stream>>>(W1, Wc, W2, W1f, WcTf, W2f);
  k_stageA<<<dim3(MTA,Bn), dim3(256), 0, stream>>>(x, prw, prb, W1f, b1, n1w, n1b, WcTf, supT);
  k_stageB<<<dim3(54*Bn), dim3(256), 0, stream>>>(adj, supT, cbv, n2w, n2b, W2f, bl2, x, (float*)d_out);
}